// Round 18
// baseline (668.623 us; speedup 1.0000x reference)
//
#include <hip/hip_runtime.h>
#include <hip/hip_bf16.h>

// EnhancedOFTLinearLayer: out = x @ (W @ blockdiag(cayley(R)))^T + bias
// Round 17: bisected grid-fusion retry. k_chain1 fuses {build_M, G, G2||H}
// with a software grid barrier (512 blocks, 45KB LDS -> 2 blocks/CU
// guaranteed co-resident; __syncthreads between sequential mm calls fixes
// the cross-wave LDS WAR that plausibly NaN'd round 12). Everything from
// k_init onward byte-identical to round 16.

typedef unsigned short u16;
typedef __attribute__((ext_vector_type(8))) __bf16 bf16x8;
typedef __attribute__((ext_vector_type(4))) float f32x4;
typedef __attribute__((ext_vector_type(8))) unsigned short u16x8;
typedef __attribute__((ext_vector_type(4))) unsigned short u16x4;

#define C0   1.000001f   /* 1 + 1e-6 */
#define C1Q  2.000001f   /* 1 + C0   */
#define AS1 __attribute__((address_space(1)))
#define AS3 __attribute__((address_space(3)))
#define NBLK 512

__device__ __forceinline__ u16 f2bf(float x) {
  union { float f; unsigned u; } v; v.f = x;
  return (u16)((v.u + 0x7fffu + ((v.u >> 16) & 1u)) >> 16);
}
__device__ __forceinline__ float bf2f(u16 h) {
  union { float f; unsigned u; } v; v.u = ((unsigned)h) << 16; return v.f;
}

// ---- software grid barrier (all NBLK blocks resident by construction) ------
__device__ __forceinline__ void grid_sync(unsigned* bar) {
  __syncthreads();
  if (threadIdx.x == 0) {
    __threadfence();
    unsigned g = __hip_atomic_load(bar + 1, __ATOMIC_RELAXED,
                                   __HIP_MEMORY_SCOPE_AGENT);
    unsigned a = __hip_atomic_fetch_add(bar, 1u, __ATOMIC_ACQ_REL,
                                        __HIP_MEMORY_SCOPE_AGENT);
    if (a == NBLK - 1u) {
      __hip_atomic_store(bar, 0u, __ATOMIC_RELAXED, __HIP_MEMORY_SCOPE_AGENT);
      __hip_atomic_store(bar + 1, g + 1u, __ATOMIC_RELEASE,
                         __HIP_MEMORY_SCOPE_AGENT);
    } else {
      while (__hip_atomic_load(bar + 1, __ATOMIC_ACQUIRE,
                               __HIP_MEMORY_SCOPE_AGENT) == g)
        __builtin_amdgcn_s_sleep(1);
    }
    __threadfence();
  }
  __syncthreads();
}

// ------- recentered-Newton coefficient cascade from t = tr(G^4) -------------
__device__ __forceinline__ void get_coefs(float t, float* C) {
  float lam = powf(t, 0.25f);
  float a = 2.0f / (C0 * C0 + lam);
  float e = (lam - C0 * C0) / (lam + C0 * C0);
  float sq = e * e, c1 = 2.0f / (2.0f - sq);
  C[0] = a; C[1] = 2.0f * c1; C[2] = -c1 * a;
  C[3] = 2.0f * c1 * a; C[4] = -c1 * a * a;
  e = sq / (2.0f - sq); sq = e * e;
  float c2 = 2.0f / (2.0f - sq);
  C[5] = 2.0f * c2; C[6] = -c2;
  e = sq / (2.0f - sq); sq = e * e;
  float c3 = 2.0f / (2.0f - sq);
  C[7] = 2.0f * c3; C[8] = -c3;
}

// ---------------- k_chain1: build_M -> G -> {G2+frob, H} --------------------
// mm64: one 64x64 tile, C = A @ B^T (all bf16), 5-slot ring, lead-3.
__device__ void mm64(int tile, const u16* __restrict__ Ah,
                     const u16* __restrict__ Bh, u16* __restrict__ Cnh,
                     int frob, u16* sA, u16* sB, float* fred,
                     float* __restrict__ part) {
  const int tid = threadIdx.x;
  const int z = tile >> 6, tl = tile & 63;
  const size_t zb = (size_t)z * 262144;
  const int m0 = (tl >> 3) * 64, n0 = (tl & 7) * 64;
  const int lane = tid & 63, wave = tid >> 6;
  const int wr = wave >> 1, wc = wave & 1;
  const int c15 = lane & 15, lk = lane >> 4;
  const int srow = tid >> 2, sg = (tid & 3) ^ (srow & 3);
  f32x4 acc[2][2] = {};
  const u16* pa = Ah + zb + (size_t)(m0 + srow) * 512 + sg * 8;
  const u16* pb = Bh + zb + (size_t)(n0 + srow) * 512 + sg * 8;

  int jn = 0, js = 0;
  auto STG = [&]() {
    if (jn < 16) {
      const int off = jn << 5;
      __builtin_amdgcn_global_load_lds((const AS1 void*)(pa + off),
                                       (AS3 void*)(sA + js * 2048 + tid * 8), 16, 0, 0);
      __builtin_amdgcn_global_load_lds((const AS1 void*)(pb + off),
                                       (AS3 void*)(sB + js * 2048 + tid * 8), 16, 0, 0);
    }
    ++jn; js = (js == 4) ? 0 : js + 1;
  };

  STG(); STG(); STG();
  int rs = 0;
  for (int t = 0; t < 16; ++t) {
    STG();
    if (t < 13)      asm volatile("s_waitcnt vmcnt(6)" ::: "memory");
    else if (t == 13) asm volatile("s_waitcnt vmcnt(4)" ::: "memory");
    else if (t == 14) asm volatile("s_waitcnt vmcnt(2)" ::: "memory");
    else              asm volatile("s_waitcnt vmcnt(0)" ::: "memory");
    __builtin_amdgcn_s_barrier();
    bf16x8 a2[2], b2[2];
#pragma unroll
    for (int i = 0; i < 2; ++i) {
      const int fr = wr * 32 + i * 16 + c15;
      a2[i] = *reinterpret_cast<const bf16x8*>(
          &sA[rs * 2048 + fr * 32 + ((lk ^ (fr & 3)) * 8)]);
    }
#pragma unroll
    for (int j = 0; j < 2; ++j) {
      const int fc = wc * 32 + j * 16 + c15;
      b2[j] = *reinterpret_cast<const bf16x8*>(
          &sB[rs * 2048 + fc * 32 + ((lk ^ (fc & 3)) * 8)]);
    }
#pragma unroll
    for (int i = 0; i < 2; ++i)
#pragma unroll
      for (int j = 0; j < 2; ++j)
        acc[i][j] = __builtin_amdgcn_mfma_f32_16x16x32_bf16(a2[i], b2[j], acc[i][j], 0, 0, 0);
    rs = (rs == 4) ? 0 : rs + 1;
  }
  float fs = 0.f;
#pragma unroll
  for (int i = 0; i < 2; ++i)
#pragma unroll
    for (int j = 0; j < 2; ++j) {
      const int rowb = m0 + wr * 32 + i * 16 + lk * 4;
      const int col  = n0 + wc * 32 + j * 16 + c15;
#pragma unroll
      for (int r = 0; r < 4; ++r) {
        u16 h = f2bf(acc[i][j][r]);
        Cnh[zb + (size_t)(rowb + r) * 512 + col] = h;
        if (frob) { float v = bf2f(h); fs += v * v; }
      }
    }
  if (frob) {
    for (int off = 32; off; off >>= 1) fs += __shfl_down(fs, off, 64);
    if ((tid & 63) == 0) fred[tid >> 6] = fs;
    __syncthreads();
    if (tid == 0) part[tile] = fred[0] + fred[1] + fred[2] + fred[3];
    __syncthreads();
  }
}

__device__ __forceinline__ void conv16k(const float* __restrict__ src,
                                        u16* __restrict__ dst) {
  const size_t base = (size_t)blockIdx.x * 16384;
#pragma unroll
  for (int g = 0; g < 8; ++g) {
    const size_t off = base + g * 2048 + (size_t)threadIdx.x * 8;
    float4 f0 = *reinterpret_cast<const float4*>(src + off);
    float4 f1 = *reinterpret_cast<const float4*>(src + off + 4);
    u16x8 w;
    w[0] = f2bf(f0.x); w[1] = f2bf(f0.y); w[2] = f2bf(f0.z); w[3] = f2bf(f0.w);
    w[4] = f2bf(f1.x); w[5] = f2bf(f1.y); w[6] = f2bf(f1.z); w[7] = f2bf(f1.w);
    *reinterpret_cast<u16x8*>(dst + off) = w;
  }
}

__global__ __launch_bounds__(256, 2)
void k_chain1(const float* __restrict__ R, const float* __restrict__ W,
              u16* Mh, u16* Ml, u16* G, u16* G2, u16* H,
              u16* W_bf, float* part, unsigned* bar) {
  __shared__ __align__(16) u16 sA[5 * 2048], sB[5 * 2048];   // 40 KiB
  __shared__ float t1[32][33];
  __shared__ float fred[4];
  const int bid = blockIdx.x, tid = threadIdx.x;

  // step 0: M = c0 I + 0.5(R - R^T) hi/lo pair; 4 32x32 tiles per block
  {
    const int ly = tid >> 5, lx = tid & 31;
    for (int i4 = 0; i4 < 4; ++i4) {
      const int t = bid * 4 + i4;
      const int n = t >> 8, rem = t & 255;
      const int tr = (rem >> 4) * 32, tc = (rem & 15) * 32;
      const float* Rb = R + (size_t)n * 262144;
      float a[4];
#pragma unroll
      for (int i = 0; i < 4; ++i) {
        a[i] = Rb[(size_t)(tr + ly + i * 8) * 512 + tc + lx];
        t1[ly + i * 8][lx] = Rb[(size_t)(tc + ly + i * 8) * 512 + tr + lx];
      }
      __syncthreads();
#pragma unroll
      for (int i = 0; i < 4; ++i) {
        const int r = tr + ly + i * 8, c = tc + lx;
        float m = 0.5f * (a[i] - t1[lx][ly + i * 8]) + (r == c ? C0 : 0.0f);
        u16 h = f2bf(m);
        const size_t idx = (size_t)n * 262144 + (size_t)r * 512 + c;
        Mh[idx] = h; Ml[idx] = f2bf(m - bf2f(h));
      }
      __syncthreads();
    }
  }
  grid_sync(bar);
  // step 1: G = M@M^T  (+ W chunks 0,1)
  mm64(bid, Mh, Mh, G, 0, sA, sB, fred, part);
  conv16k(W, W_bf);
  grid_sync(bar);
  // step 2: G2 = G@G^T (+frob partials) ; H = M@G  (+ W chunks 2,3)
  mm64(bid, G, G, G2, 1, sA, sB, fred, part);
  __syncthreads();               // cross-wave LDS WAR before ring reuse
  mm64(bid, Mh, G, H, 0, sA, sB, fred, part);
  conv16k(W + 8388608, W_bf + 8388608);
}

// ---- 3a) k_init: coefs; X1 = g0 I + g1 M + g2 G + g3 H ; T2 elementwise ----
__global__ __launch_bounds__(256) void k_init(const u16* __restrict__ Mh,
                                              const u16* __restrict__ Ml,
                                              const u16* __restrict__ G,
                                              const u16* __restrict__ G2,
                                              const u16* __restrict__ H,
                                              const float* __restrict__ part,
                                              float* __restrict__ coef,
                                              u16* __restrict__ X1,
                                              u16* __restrict__ T2) {
  __shared__ float sp[64];
  __shared__ float sc[13];
  const int n = blockIdx.x >> 7;              // 128 blocks per batch
  if (threadIdx.x < 64) sp[threadIdx.x] = part[n * 64 + threadIdx.x];
  __syncthreads();
  if (threadIdx.x == 0) {
    float s = 0.f;
    for (int i = 0; i < 64; ++i) s += sp[i];  // fixed order: deterministic
    float C[9];
    get_coefs(s, C);
#pragma unroll
    for (int k = 0; k < 9; ++k) sc[k] = C[k];
    sc[9]  = 2.0f * C0 * C[3];   // g0
    sc[10] = -C[3];              // g1
    sc[11] = 2.0f * C0 * C[4];   // g2
    sc[12] = -C[4];              // g3
    coef[n] = C[0];
    coef[8 + n]  = C[1]; coef[16 + n] = C[2];
    coef[24 + n] = C[3]; coef[32 + n] = C[4];
    coef[40 + n] = C[5]; coef[48 + n] = C[6];
    coef[56 + n] = C[7]; coef[64 + n] = C[8];
  }
  __syncthreads();
  const size_t base = ((size_t)blockIdx.x * 256 + threadIdx.x) * 8;
  const int r  = (int)((base >> 9) & 511);
  const int c0 = (int)(base & 511);
  u16x8 mh = *reinterpret_cast<const u16x8*>(Mh + base);
  u16x8 ml = *reinterpret_cast<const u16x8*>(Ml + base);
  u16x8 g  = *reinterpret_cast<const u16x8*>(G  + base);
  u16x8 g2 = *reinterpret_cast<const u16x8*>(G2 + base);
  u16x8 hh = *reinterpret_cast<const u16x8*>(H  + base);
  u16x8 x1, t2;
#pragma unroll
  for (int e = 0; e < 8; ++e) {
    float m = bf2f(mh[e]) + bf2f(ml[e]);
    float gv = bf2f(g[e]);
    x1[e] = f2bf((r == c0 + e ? sc[9] : 0.0f) + sc[10] * m + sc[11] * gv +
                 sc[12] * bf2f(hh[e]));
    t2[e] = f2bf(sc[3] * gv + sc[4] * bf2f(g2[e]));
  }
  *reinterpret_cast<u16x8*>(X1 + base) = x1;
  *reinterpret_cast<u16x8*>(T2 + base) = t2;
}

// ---------------- batched bf16 mm: C = cd*D + cs*(A @ B^T) ------------------
#define BMM_FRAGS(rs)                                                          \
  bf16x8 a[2], b[2], al2[2], bl2[2];                                           \
  _Pragma("unroll")                                                            \
  for (int i = 0; i < 2; ++i) {                                                \
    const int fr = wr * 32 + i * 16 + c15;                                     \
    const int ia = (rs) * 2048 + fr * 32 + ((lk ^ (fr & 3)) * 8);              \
    a[i] = *reinterpret_cast<const bf16x8*>(&sA[ia]);                          \
    if constexpr (PROD3) al2[i] = *reinterpret_cast<const bf16x8*>(&sAl[ia]);  \
  }                                                                            \
  _Pragma("unroll")                                                            \
  for (int j = 0; j < 2; ++j) {                                                \
    const int fc = wc * 32 + j * 16 + c15;                                     \
    const int ib = (rs) * 2048 + fc * 32 + ((lk ^ (fc & 3)) * 8);              \
    b[j] = *reinterpret_cast<const bf16x8*>(&sB[ib]);                          \
    if constexpr (PROD3) bl2[j] = *reinterpret_cast<const bf16x8*>(&sBl[ib]);  \
  }                                                                            \
  _Pragma("unroll")                                                            \
  for (int i = 0; i < 2; ++i)                                                  \
    _Pragma("unroll")                                                          \
    for (int j = 0; j < 2; ++j) {                                              \
      acc[i][j] = __builtin_amdgcn_mfma_f32_16x16x32_bf16(a[i], b[j], acc[i][j], 0, 0, 0); \
      if constexpr (PROD3) {                                                   \
        acc[i][j] = __builtin_amdgcn_mfma_f32_16x16x32_bf16(a[i],   bl2[j], acc[i][j], 0, 0, 0); \
        acc[i][j] = __builtin_amdgcn_mfma_f32_16x16x32_bf16(al2[i], b[j],   acc[i][j], 0, 0, 0); \
      }                                                                        \
    }

#define BMM_WAIT(SEL)                                                          \
  if ((SEL) == 0) {                                                            \
    if constexpr (PROD3) asm volatile("s_waitcnt vmcnt(12)" ::: "memory");     \
    else                 asm volatile("s_waitcnt vmcnt(6)" ::: "memory");      \
  } else if ((SEL) == 1) {                                                     \
    if constexpr (PROD3) asm volatile("s_waitcnt vmcnt(8)" ::: "memory");      \
    else                 asm volatile("s_waitcnt vmcnt(4)" ::: "memory");      \
  } else if ((SEL) == 2) {                                                     \
    if constexpr (PROD3) asm volatile("s_waitcnt vmcnt(4)" ::: "memory");      \
    else                 asm volatile("s_waitcnt vmcnt(2)" ::: "memory");      \
  } else {                                                                     \
    asm volatile("s_waitcnt vmcnt(0)" ::: "memory");                           \
  }

template <int PROD3, int DMODE, int OMODE, int DUAL, int FROB, int VOUT = 0>
__global__ __launch_bounds__(256)
void k_bmm(const u16* __restrict__ Ah, const u16* __restrict__ Al,
           const u16* __restrict__ Bh, const u16* __restrict__ Bl,
           const u16* __restrict__ Dh, const u16* __restrict__ Dl,
           u16* __restrict__ Cnh, u16* __restrict__ Cnl,
           u16* __restrict__ Cth, u16* __restrict__ Ctl,
           float cd, float cs,
           const float* __restrict__ cdp, const float* __restrict__ csp,
           const float* __restrict__ cvsrc, u16* __restrict__ cvdst, int zmm,
           const u16* __restrict__ A2, const u16* __restrict__ B2,
           const u16* __restrict__ D2, u16* __restrict__ C2,
           float* __restrict__ part) {
  __shared__ __align__(16) u16 sA[5 * 2048], sB[5 * 2048];
  __shared__ __align__(16) u16 sAl[PROD3 ? 5 * 2048 : 8];
  __shared__ __align__(16) u16 sBl[PROD3 ? 5 * 2048 : 8];
  __shared__ float fred[FROB ? 4 : 1];

  if ((int)blockIdx.z >= zmm) {   // conversion side-channel
    const int zi = ((int)blockIdx.z - zmm) * 64 + blockIdx.y * 8 + blockIdx.x;
    const int chunk = zi >> 7;
    const int base = (zi & 127) * 256 + (int)threadIdx.x;
    const float* src = cvsrc + (size_t)chunk * 4194304;
    u16* dst = cvdst + (size_t)chunk * 4194304;
#pragma unroll
    for (int e = 0; e < 16; ++e) {
      const size_t g = (size_t)(base + e * 32768) * 8;
      float4 f0 = *reinterpret_cast<const float4*>(src + g);
      float4 f1 = *reinterpret_cast<const float4*>(src + g + 4);
      u16x8 w;
      w[0] = f2bf(f0.x); w[1] = f2bf(f0.y); w[2] = f2bf(f0.z); w[3] = f2bf(f0.w);
      w[4] = f2bf(f1.x); w[5] = f2bf(f1.y); w[6] = f2bf(f1.z); w[7] = f2bf(f1.w);
      *reinterpret_cast<u16x8*>(dst + g) = w;
    }
    return;
  }

  const int zq = DUAL ? ((blockIdx.z >> 3) & 1) : 0;
  const u16* Ah_ = (DUAL && zq) ? A2 : Ah;
  const u16* Bh_ = (DUAL && zq) ? B2 : Bh;
  const u16* Dh_ = (DUAL && zq) ? D2 : Dh;
  u16* Cnh_ = (DUAL && zq) ? C2 : Cnh;
  const size_t zb = (size_t)(blockIdx.z & 7) * 262144;
  const int tid = threadIdx.x, lane = tid & 63, wave = tid >> 6;
  const int m0 = blockIdx.y * 64, n0 = blockIdx.x * 64;
  const int wr = wave >> 1, wc = wave & 1;
  const int c15 = lane & 15, lk = lane >> 4;
  const int srow = tid >> 2;
  const int sg = (tid & 3) ^ (srow & 3);
  f32x4 acc[2][2] = {};
  const u16* pa = Ah_ + zb + (size_t)(m0 + srow) * 512 + sg * 8;
  const u16* pb = Bh_ + zb + (size_t)(n0 + srow) * 512 + sg * 8;
  const u16* pal = PROD3 ? Al + zb + (size_t)(m0 + srow) * 512 + sg * 8 : pa;
  const u16* pbl = PROD3 ? Bl + zb + (size_t)(n0 + srow) * 512 + sg * 8 : pb;

  int jn = 0, js = 0;
  auto STG = [&]() {
    if (jn < 16) {
      const int off = jn << 5;
      __builtin_amdgcn_global_load_lds((const AS1 void*)(pa + off),
                                       (AS3 void*)(sA + js * 2048 + tid * 8), 16, 0, 0);
      __builtin_amdgcn_global_load_lds((const AS1 void*)(pb + off),
                                       (AS3 void*)(sB + js * 2048 + tid * 8), 16, 0, 0);
      if constexpr (PROD3) {
        __builtin_amdgcn_global_load_lds((const AS1 void*)(pal + off),
                                         (AS3 void*)(sAl + js * 2048 + tid * 8), 16, 0, 0);
        __builtin_amdgcn_global_load_lds((const AS1 void*)(pbl + off),
                                         (AS3 void*)(sBl + js * 2048 + tid * 8), 16, 0, 0);
      }
    }
    ++jn; js = (js == 4) ? 0 : js + 1;
  };

  STG(); STG(); STG();
  int rs = 0;
  for (int t = 0; t < 13; ++t) {
    STG();
    BMM_WAIT(0)
    __builtin_amdgcn_s_barrier();
    BMM_FRAGS(rs)
    rs = (rs == 4) ? 0 : rs + 1;
  }
  STG();
  BMM_WAIT(1)
  __builtin_amdgcn_s_barrier();
  { BMM_FRAGS(rs) }
  rs = (rs == 4) ? 0 : rs + 1;
  STG();
  BMM_WAIT(2)
  __builtin_amdgcn_s_barrier();
  { BMM_FRAGS(rs) }
  rs = (rs == 4) ? 0 : rs + 1;
  STG();
  BMM_WAIT(3)
  __builtin_amdgcn_s_barrier();
  { BMM_FRAGS(rs) }

  const float cdL = cdp ? cdp[blockIdx.z & 7] : cd;
  const float csL = csp ? csp[blockIdx.z & 7] : cs;
  float fs = 0.f;
#pragma unroll
  for (int i = 0; i < 2; ++i)
#pragma unroll
    for (int j = 0; j < 2; ++j) {
      const int rowb = m0 + wr * 32 + i * 16 + lk * 4;
      const int col  = n0 + wc * 32 + j * 16 + c15;
      u16 hv[4], lv[4];
#pragma unroll
      for (int r = 0; r < 4; ++r) {
        float val = csL * acc[i][j][r];
        float dv = 0.f;
        if constexpr (DMODE >= 1) {
          dv = bf2f(Dh_[zb + (size_t)(rowb + r) * 512 + col]);
          if constexpr (DMODE == 2) dv += bf2f(Dl[zb + (size_t)(rowb + r) * 512 + col]);
        }
        float nval, tval;
        if constexpr (VOUT) { tval = val; nval = cdL * dv - val; }
        else { nval = tval = val + cdL * dv; }
        u16 nh = f2bf(nval);
        if constexpr (OMODE & 1) Cnh_[zb + (size_t)(rowb + r) * 512 + col] = nh;
        if constexpr (FROB) { float v = bf2f(nh); fs += v * v; }
        if constexpr (OMODE & 2)
          Cnl[zb + (size_t)(rowb + r) * 512 + col] = f2bf(nval - bf2f(nh));
        if constexpr (OMODE & 12) {
          u16 th = f2bf(tval);
          hv[r] = th;
          if constexpr (OMODE & 8) lv[r] = f2bf(tval - bf2f(th));
        }
      }
      if constexpr (OMODE & 4) {
        u16x4 v; v[0] = hv[0]; v[1] = hv[1]; v[2] = hv[2]; v[3] = hv[3];
        *reinterpret_cast<u16x4*>(&Cth[zb + (size_t)col * 512 + rowb]) = v;
      }
      if constexpr (OMODE & 8) {
        u16x4 v; v[0] = lv[0]; v[1] = lv[1]; v[2] = lv[2]; v[3] = lv[3];
        *reinterpret_cast<u16x4*>(&Ctl[zb + (size_t)col * 512 + rowb]) = v;
      }
    }
  if constexpr (FROB) {
    for (int off = 32; off; off >>= 1) fs += __shfl_down(fs, off, 64);
    if ((tid & 63) == 0) fred[tid >> 6] = fs;
    __syncthreads();
    if (tid == 0 && (int)blockIdx.z < 8)
      part[(blockIdx.z & 7) * 64 + blockIdx.y * 8 + blockIdx.x] =
          fred[0] + fred[1] + fred[2] + fred[3];
  }
}

// ---------------- tw = W_bf @ blockdiag(Q)  (B = Qt, 5-slot ring) -----------
__global__ __launch_bounds__(256)
void k_twmm(const u16* __restrict__ W, const u16* __restrict__ Qt,
            u16* __restrict__ tw) {
  __shared__ __align__(16) u16 sA[5 * 2048], sB[5 * 2048];
  const int z = blockIdx.z;
  const size_t zb = (size_t)z * 262144;
  const int tid = threadIdx.x, lane = tid & 63, wave = tid >> 6;
  const int m0 = blockIdx.y * 64, n0 = blockIdx.x * 64;
  const int wr = wave >> 1, wc = wave & 1;
  const int c15 = lane & 15, lk = lane >> 4;
  const int srow = tid >> 2;
  const int sg = (tid & 3) ^ (srow & 3);
  f32x4 acc[2][2] = {};
  const u16* pa = W + (size_t)(m0 + srow) * 4096 + z * 512 + sg * 8;
  const u16* pb = Qt + zb + (size_t)(n0 + srow) * 512 + sg * 8;

  int jn = 0, js = 0;
  auto STG = [&]() {
    if (jn < 16) {
      const int off = jn << 5;
      __builtin_amdgcn_global_load_lds((const AS1 void*)(pa + off),
                                       (AS3 void*)(sA + js * 2048 + tid * 8), 16, 0, 0);
      __builtin_amdgcn_global_load_lds((const AS1 void*)(pb + off),
                                       (AS3 void*)(sB + js * 2048 + tid * 8), 16, 0, 0);
    }
    ++jn; js = (js == 4) ? 0 : js + 1;
  };

#define TW_FRAGS(rs)                                                           \
  {                                                                            \
    bf16x8 a[2], b[2];                                                         \
    _Pragma("unroll")                                                          \
    for (int i = 0; i < 2; ++i) {                                              \
      const int fr = wr * 32 + i * 16 + c15;                                   \
      a[i] = *reinterpret_cast<const bf16x8*>(                                 \
          &sA[(rs) * 2048 + fr * 32 + ((lk ^ (fr & 3)) * 8)]);                 \
    }                                                                          \
    _Pragma("unroll")                                                          \
    for (int j = 0; j < 2; ++j) {                                              \
      const int fc = wc * 32 + j * 16 + c15;                                   \
      b[j] = *reinterpret_cast<const bf16x8*>(                                 \
          &sB[(rs) * 2048 + fc * 32 + ((lk ^ (fc & 3)) * 8)]);                 \
    }                                                                          \
    _Pragma("unroll")                                                          \
    for (int i = 0; i < 2; ++i)                                                \
      _Pragma("unroll")                                                        \
      for (int j = 0; j < 2; ++j)                                              \
        acc[i][j] = __builtin_amdgcn_mfma_f32_16x16x32_bf16(a[i], b[j], acc[i][j], 0, 0, 0); \
  }

  STG(); STG(); STG();
  int rs = 0;
  for (int t = 0; t < 13; ++t) {
    STG();
    asm volatile("s_waitcnt vmcnt(6)" ::: "memory");
    __builtin_amdgcn_s_barrier();
    TW_FRAGS(rs)
    rs = (rs == 4) ? 0 : rs + 1;
  }
  STG();
  asm volatile("s_waitcnt vmcnt(4)" ::: "memory");
  __builtin_amdgcn_s_barrier();
  TW_FRAGS(rs)
  rs = (rs == 4) ? 0 : rs + 1;
  STG();
  asm volatile("s_waitcnt vmcnt(2)" ::: "memory");
  __builtin_amdgcn_s_barrier();
  TW_FRAGS(rs)
  rs = (rs == 4) ? 0 : rs + 1;
  STG();
  asm volatile("s_waitcnt vmcnt(0)" ::: "memory");
  __builtin_amdgcn_s_barrier();
  TW_FRAGS(rs)

#pragma unroll
  for (int i = 0; i < 2; ++i)
#pragma unroll
    for (int j = 0; j < 2; ++j) {
      const int rowb = m0 + wr * 32 + i * 16 + lk * 4;
      const int col  = z * 512 + n0 + wc * 32 + j * 16 + c15;
#pragma unroll
      for (int r = 0; r < 4; ++r)
        tw[(size_t)(rowb + r) * 4096 + col] = f2bf(acc[i][j][r]);
    }
}

// ---------------- out = x_bf @ tw^T + bias (round-6, verbatim) --------------
#define NSL 18

#define RD_A3(dst, MH)                                                         \
  _Pragma("unroll")                                                            \
  for (int m = 0; m < 4; ++m)                                                  \
    dst[m] = *reinterpret_cast<const bf16x8*>(                                 \
        &lds[aslot * 4096 + ((MH) * 64 + m * 16 + c15) * 32 + gsw * 8]);

#define RD_B3(dst)                                                             \
  _Pragma("unroll")                                                            \
  for (int n = 0; n < 4; ++n)                                                  \
    dst[n] = *reinterpret_cast<const bf16x8*>(                                 \
        &lds[bslot * 4096 + (bq64 + n * 16 + c15) * 32 + gsw * 8]);

#define MFMA16(afX, bfX, MH)                                                   \
  __builtin_amdgcn_s_setprio(1);                                               \
  _Pragma("unroll")                                                            \
  for (int m = 0; m < 4; ++m)                                                  \
    _Pragma("unroll")                                                          \
    for (int n = 0; n < 4; ++n)                                                \
      acc[(MH) * 4 + m][n] = __builtin_amdgcn_mfma_f32_16x16x32_bf16(          \
          afX[m], bfX[n], acc[(MH) * 4 + m][n], 0, 0, 0);                      \
  __builtin_amdgcn_s_setprio(0);

#define TILE32(WM)                                                             \
  {                                                                            \
    int aslot = s0 + wr;            if (aslot >= NSL) aslot -= NSL;            \
    int bslot = s0 + 2 + (wc >> 1); if (bslot >= NSL) bslot -= NSL;            \
    STAGE(); STAGE();                                                          \
    RD_B3(bfr)                                                                 \
    RD_A3(afA, 0)                                                              \
    MFMA16(afA, bfr, 0)                                                        \
    STAGE(); STAGE();                                                          \
    RD_A3(afB, 1)                                                              \
    MFMA16(afB, bfr, 1)                                                        \
    if ((WM) == 1) asm volatile("s_waitcnt vmcnt(8)" ::: "memory");            \
    if ((WM) == 2) asm volatile("s_waitcnt vmcnt(4)" ::: "memory");            \
    if ((WM) == 3) asm volatile("s_waitcnt vmcnt(0)" ::: "memory");            \
    if ((WM) != 0) {                                                           \
      __builtin_amdgcn_s_barrier();                                            \
      __builtin_amdgcn_sched_barrier(0);                                       \
    }                                                                          \
    s0 += 4; if (s0 >= NSL) s0 -= NSL;                                         \
  }

__global__ __launch_bounds__(512, 2)
void k_gemm256(const u16* __restrict__ A, const u16* __restrict__ B,
               const float* __restrict__ bias,
               float* __restrict__ C, int N, int K) {
  __shared__ __align__(16) u16 lds[NSL * 4096];   // 144 KiB
  const int tid = threadIdx.x, lane = tid & 63, wave = tid >> 6;
  int bid = blockIdx.y * gridDim.x + blockIdx.x;
  const int cpx = (gridDim.x * gridDim.y) >> 3;
  bid = (bid & 7) * cpx + (bid >> 3);
  const int nbx = N >> 8;
  const int bx = bid % nbx, by = bid / nbx;
  const int m0 = by << 8, n0 = bx << 8;
  const int wr = wave >> 2, wc = wave & 3;
  const int srow = tid >> 2;
  const int sgc  = (tid & 3) ^ ((srow >> 1) & 3);
  const int c15 = lane & 15, lq = lane >> 4;
  const int gsw = lq ^ ((c15 >> 1) & 3);
  const int bq64 = (wc & 1) * 64;
  const int NT = K >> 5;

  f32x4 acc[8][4] = {};
  bf16x8 afA[4], afB[4], bfr[4];

  int jn = 0, js = 0;
  auto STAGE = [&]() {
    if (jn < 4 * NT) {
      const int t = jn >> 2, q = jn & 3;
      const u16* srcb = (q < 2)
          ? A + (size_t)(m0 + q * 128 + srow) * (size_t)K
          : B + (size_t)(n0 + (q - 2) * 128 + srow) * (size_t)K;
      const u16* src = srcb + (t << 5) + sgc * 8;
      u16* dst = (u16*)lds + js * 4096 + tid * 8;
      __builtin_amdgcn_global_load_lds(
          (const AS1 void*)src, (AS3 void*)dst, 16, 0, 0);
    }
    ++jn; js = (js == NSL - 1) ? 0 : js + 1;
  };

#pragma unroll
  for (int i = 0; i < 12; ++i) STAGE();
  asm volatile("s_waitcnt vmcnt(8)" ::: "memory");
  __builtin_amdgcn_s_barrier();
  __builtin_amdgcn_sched_barrier(0);

  int s0 = 0;
  for (int tau = 0; tau < NT - 3; ++tau) {
    TILE32(1)
  }
  TILE32(2)
  TILE32(3)
  TILE32(0)

#pragma unroll
  for (int n = 0; n < 4; ++n) {
    const int col = n0 + wc * 64 + n * 16 + c15;
    const float bv = bias[col];
#pragma unroll
    for (int mi = 0; mi < 8; ++mi) {
      const int rowb = m0 + wr * 128 + mi * 16 + (lq << 2);
#pragma unroll
      for (int r = 0; r < 4; ++r)
        C[(size_t)(rowb + r) * N + col] = acc[mi][n][r] + bv;
    }
  }
}

extern "C" void kernel_launch(void* const* d_in, const int* in_sizes, int n_in,
                              void* d_out, int out_size, void* d_ws, size_t ws_size,
                              hipStream_t stream) {
  const float* W    = (const float*)d_in[0];   // [4096,4096]
  const float* bias = (const float*)d_in[1];   // [4096]
  const float* x    = (const float*)d_in[2];   // [4,2048,4096]
  const float* R    = (const float*)d_in[3];   // [8,512,512]
  float* out = (float*)d_out;

  char* ws = (char*)d_ws;
  u16* x_bf = (u16*)(ws);                      //  64 MiB
  u16* tw   = (u16*)(ws + 67108864);           //  32 MiB
  u16* W_bf = (u16*)(ws + 100663296);          //  32 MiB

  // scratch arena = d_out (128 MiB; fully overwritten by k_gemm256)
  char* arena = (char*)d_out;
  auto slot = [&](int i) -> u16* { return (u16*)(arena + (size_t)i * 4194304); };
  u16 *Mh = slot(0), *Ml = slot(1);
  u16 *G = slot(2), *G2 = slot(3), *H = slot(4);
  u16 *T2 = slot(6), *X1 = slot(7), *X2 = slot(8), *T3 = slot(9);
  u16 *X3h = slot(10), *X3l = slot(11), *X3th = slot(12), *X3tl = slot(13);
  u16 *Tpth = slot(14), *Tptl = slot(15);
  u16 *Vh = slot(16), *Vl = slot(17);
  u16 *Qt = slot(20);
  float* coef = (float*)(arena + (size_t)21 * 4194304);   // 72 floats
  float* part = coef + 1024;                              // 512 floats
  unsigned* bar = (unsigned*)(arena + (size_t)22 * 4194304);

  const u16* NUL = nullptr;
  const float* NULF = nullptr;
  u16* NULW = nullptr;
  float* NULP = nullptr;
  const dim3 gC2(8, 8, 12);     // 8 mm + 4 conv planes (2 chunks)
  const dim3 gD2(8, 8, 20);     // 16 mm (DUAL) + 4 conv planes (2 chunks)

  // 1-3) fused: M pair ; G = M@M^T ; {G2 = G@G^T + frob || H = M@G}
  //      (+ all 4 W chunks)
  hipMemsetAsync(bar, 0, 64, stream);
  k_chain1<<<dim3(NBLK), 256, 0, stream>>>(R, W, Mh, Ml, G, G2, H,
                                           W_bf, part, bar);
  // 4) coefficients ; X1 (elementwise) + T2
  k_init<<<1024, 256, 0, stream>>>(Mh, Ml, G, G2, H, part, coef, X1, T2);
  // 5) DUAL: X2 = 2c2*X1 - c2*(X1@T2)  ||  T3 = 2c2*T2 - c2*(T2@T2)
  //    (+ x chunks 0,1)
  k_bmm<0, 1, 1, 1, 0><<<gD2, 256, 0, stream>>>(X1, NUL, T2, NUL, X1, NUL,
      X2, NULW, NULW, NULW, 0.f, 0.f, coef + 40, coef + 48,
      x, x_bf, 16, T2, T2, T2, T3, NULP);
  // 6) X3 = 2c3*X2 - c3*(X2@T3), pairs + transposed pairs  (+ x chunks 2,3)
  k_bmm<0, 1, 15, 0, 0><<<gC2, 256, 0, stream>>>(X2, NUL, T3, NUL, X2, NUL,
      X3h, X3l, X3th, X3tl, 0.f, 0.f, coef + 56, coef + 64,
      x + (size_t)2 * 4194304, x_bf + (size_t)2 * 4194304, 8,
      NUL, NUL, NUL, NULW, NULP);
  // 7) VOUT: Tp^T = (M@X3)^T pairs  AND  V = C1Q*X3 - Tp pairs
  //    (+ x chunks 4,5)
  k_bmm<1, 2, 15, 0, 0, 1><<<gC2, 256, 0, stream>>>(Mh, Ml, X3th, X3tl,
      X3h, X3l, Vh, Vl, Tpth, Tptl, C1Q, 1.f, NULF, NULF,
      x + (size_t)4 * 4194304, x_bf + (size_t)4 * 4194304, 8,
      NUL, NUL, NUL, NULW, NULP);
  // 8) Q^T = transpose of (2V - V@Tp)  (+ x chunks 6,7)
  k_bmm<1, 2, 4, 0, 0><<<gC2, 256, 0, stream>>>(Vh, Vl, Tpth, Tptl, Vh, Vl,
      NULW, NULW, Qt, NULW, 2.f, -1.f, NULF, NULF,
      x + (size_t)6 * 4194304, x_bf + (size_t)6 * 4194304, 8,
      NUL, NUL, NUL, NULW, NULP);
  // 9) tw = W_bf @ blockdiag(Q) ; main GEMM (overwrites the arena)
  k_twmm<<<dim3(8, 64, 8), 256, 0, stream>>>(W_bf, Qt, tw);
  k_gemm256<<<dim3(16, 32), 512, 0, stream>>>(x_bf, tw, bias, out, 4096, 4096);
}

// Round 19
// 465.733 us; speedup vs baseline: 1.4356x; 1.4356x over previous
//
#include <hip/hip_runtime.h>
#include <hip/hip_bf16.h>

// EnhancedOFTLinearLayer: out = x @ (W @ blockdiag(cayley(R)))^T + bias
//   cayley(A): S = 0.5(A - A^T); Q = (I - S) @ inv((1+1e-6)I + S)
// Round 18: revert to round 16 (best known-good, 469 us). Round 17 proved
// the software grid barrier correct but uneconomical (~100 us/sync from
// cross-XCD atomic visibility); kernel launches are the cheaper sync.
// Chain: build_M -> G -> {G2+frob || H} -> init(X1,T2 elementwise) ->
// {X2 || T3} -> X3 -> {Tp + V} -> Q -> tw -> main GEMM. 10 dispatches.

typedef unsigned short u16;
typedef __attribute__((ext_vector_type(8))) __bf16 bf16x8;
typedef __attribute__((ext_vector_type(4))) float f32x4;
typedef __attribute__((ext_vector_type(8))) unsigned short u16x8;
typedef __attribute__((ext_vector_type(4))) unsigned short u16x4;

#define C0   1.000001f   /* 1 + 1e-6 */
#define C1Q  2.000001f   /* 1 + C0   */
#define AS1 __attribute__((address_space(1)))
#define AS3 __attribute__((address_space(3)))

__device__ __forceinline__ u16 f2bf(float x) {
  union { float f; unsigned u; } v; v.f = x;
  return (u16)((v.u + 0x7fffu + ((v.u >> 16) & 1u)) >> 16);
}
__device__ __forceinline__ float bf2f(u16 h) {
  union { float f; unsigned u; } v; v.u = ((unsigned)h) << 16; return v.f;
}

// ------- recentered-Newton coefficient cascade from t = tr(G^4) -------------
// C[0]=a C[1]=2c1 C[2]=-c1*a C[3]=2c1a C[4]=-c1a^2 C[5]=2c2 C[6]=-c2
// C[7]=2c3 C[8]=-c3
__device__ __forceinline__ void get_coefs(float t, float* C) {
  float lam = powf(t, 0.25f);
  float a = 2.0f / (C0 * C0 + lam);
  float e = (lam - C0 * C0) / (lam + C0 * C0);
  float sq = e * e, c1 = 2.0f / (2.0f - sq);
  C[0] = a; C[1] = 2.0f * c1; C[2] = -c1 * a;
  C[3] = 2.0f * c1 * a; C[4] = -c1 * a * a;
  e = sq / (2.0f - sq); sq = e * e;
  float c2 = 2.0f / (2.0f - sq);
  C[5] = 2.0f * c2; C[6] = -c2;
  e = sq / (2.0f - sq); sq = e * e;
  float c3 = 2.0f / (2.0f - sq);
  C[7] = 2.0f * c3; C[8] = -c3;
}

// ---------------- 1) M = (1+1e-6)I + 0.5(R - R^T) -> bf16 hi/lo pair --------
__global__ __launch_bounds__(256) void k_build_M(const float* __restrict__ R,
                                                 u16* __restrict__ Mh,
                                                 u16* __restrict__ Ml) {
  __shared__ float t1[32][33];
  const int n = blockIdx.z;
  const int tr = blockIdx.y * 32, tc = blockIdx.x * 32;
  const int ly = threadIdx.x >> 5, lx = threadIdx.x & 31;   // 8 x 32
  const float* Rb = R + (size_t)n * 262144;
  float a[4];
#pragma unroll
  for (int i = 0; i < 4; ++i) {
    a[i] = Rb[(size_t)(tr + ly + i * 8) * 512 + tc + lx];
    t1[ly + i * 8][lx] = Rb[(size_t)(tc + ly + i * 8) * 512 + tr + lx];
  }
  __syncthreads();
#pragma unroll
  for (int i = 0; i < 4; ++i) {
    const int r = tr + ly + i * 8, c = tc + lx;
    float m = 0.5f * (a[i] - t1[lx][ly + i * 8]) + (r == c ? C0 : 0.0f);
    u16 h = f2bf(m);
    const size_t idx = (size_t)n * 262144 + (size_t)r * 512 + c;
    Mh[idx] = h;
    Ml[idx] = f2bf(m - bf2f(h));
  }
}

// ---- 3a) k_init: coefs; X1 = g0 I + g1 M + g2 G + g3 H ; T2 elementwise ----
__global__ __launch_bounds__(256) void k_init(const u16* __restrict__ Mh,
                                              const u16* __restrict__ Ml,
                                              const u16* __restrict__ G,
                                              const u16* __restrict__ G2,
                                              const u16* __restrict__ H,
                                              const float* __restrict__ part,
                                              float* __restrict__ coef,
                                              u16* __restrict__ X1,
                                              u16* __restrict__ T2) {
  __shared__ float sp[64];
  __shared__ float sc[13];
  const int n = blockIdx.x >> 7;              // 128 blocks per batch
  if (threadIdx.x < 64) sp[threadIdx.x] = part[n * 64 + threadIdx.x];
  __syncthreads();
  if (threadIdx.x == 0) {
    float s = 0.f;
    for (int i = 0; i < 64; ++i) s += sp[i];  // fixed order: deterministic
    float C[9];
    get_coefs(s, C);
#pragma unroll
    for (int k = 0; k < 9; ++k) sc[k] = C[k];
    // X1 = 2c1*X0 - c1a*(X0@G); X0 = a(2c0 I - M); X0@G = 2c0a G - a H
    sc[9]  = 2.0f * C0 * C[3];   // g0 = 4 c0 c1 a        (diagonal)
    sc[10] = -C[3];              // g1 = -2 c1 a          (M term)
    sc[11] = 2.0f * C0 * C[4];   // g2 = -2 c0 c1 a^2     (G term)
    sc[12] = -C[4];              // g3 =  c1 a^2          (H term)
    coef[n] = C[0];
    coef[8 + n]  = C[1]; coef[16 + n] = C[2];
    coef[24 + n] = C[3]; coef[32 + n] = C[4];
    coef[40 + n] = C[5]; coef[48 + n] = C[6];
    coef[56 + n] = C[7]; coef[64 + n] = C[8];
  }
  __syncthreads();
  const size_t base = ((size_t)blockIdx.x * 256 + threadIdx.x) * 8;
  const int r  = (int)((base >> 9) & 511);
  const int c0 = (int)(base & 511);
  u16x8 mh = *reinterpret_cast<const u16x8*>(Mh + base);
  u16x8 ml = *reinterpret_cast<const u16x8*>(Ml + base);
  u16x8 g  = *reinterpret_cast<const u16x8*>(G  + base);
  u16x8 g2 = *reinterpret_cast<const u16x8*>(G2 + base);
  u16x8 hh = *reinterpret_cast<const u16x8*>(H  + base);
  u16x8 x1, t2;
#pragma unroll
  for (int e = 0; e < 8; ++e) {
    float m = bf2f(mh[e]) + bf2f(ml[e]);
    float gv = bf2f(g[e]);
    x1[e] = f2bf((r == c0 + e ? sc[9] : 0.0f) + sc[10] * m + sc[11] * gv +
                 sc[12] * bf2f(hh[e]));
    t2[e] = f2bf(sc[3] * gv + sc[4] * bf2f(g2[e]));
  }
  *reinterpret_cast<u16x8*>(X1 + base) = x1;
  *reinterpret_cast<u16x8*>(T2 + base) = t2;
}

// ---------------- batched bf16 mm: C = cd*D + cs*(A @ B^T) ------------------
// 5-slot LDS ring, 3-step prefetch lead, counted vmcnt, 1 barrier/step.
// PROD3: split hi/lo 3-MFMA product. DMODE 0/1/2. OMODE bits 1/2/4/8.
// DUAL: z in [8,16) = second job. FROB: per-tile sum((bf16 out)^2) -> part
// (job A only). VOUT: normal outputs get cd*D - val, transposed get val.
#define BMM_FRAGS(rs)                                                          \
  bf16x8 a[2], b[2], al2[2], bl2[2];                                           \
  _Pragma("unroll")                                                            \
  for (int i = 0; i < 2; ++i) {                                                \
    const int fr = wr * 32 + i * 16 + c15;                                     \
    const int ia = (rs) * 2048 + fr * 32 + ((lk ^ (fr & 3)) * 8);              \
    a[i] = *reinterpret_cast<const bf16x8*>(&sA[ia]);                          \
    if constexpr (PROD3) al2[i] = *reinterpret_cast<const bf16x8*>(&sAl[ia]);  \
  }                                                                            \
  _Pragma("unroll")                                                            \
  for (int j = 0; j < 2; ++j) {                                                \
    const int fc = wc * 32 + j * 16 + c15;                                     \
    const int ib = (rs) * 2048 + fc * 32 + ((lk ^ (fc & 3)) * 8);              \
    b[j] = *reinterpret_cast<const bf16x8*>(&sB[ib]);                          \
    if constexpr (PROD3) bl2[j] = *reinterpret_cast<const bf16x8*>(&sBl[ib]);  \
  }                                                                            \
  _Pragma("unroll")                                                            \
  for (int i = 0; i < 2; ++i)                                                  \
    _Pragma("unroll")                                                          \
    for (int j = 0; j < 2; ++j) {                                              \
      acc[i][j] = __builtin_amdgcn_mfma_f32_16x16x32_bf16(a[i], b[j], acc[i][j], 0, 0, 0); \
      if constexpr (PROD3) {                                                   \
        acc[i][j] = __builtin_amdgcn_mfma_f32_16x16x32_bf16(a[i],   bl2[j], acc[i][j], 0, 0, 0); \
        acc[i][j] = __builtin_amdgcn_mfma_f32_16x16x32_bf16(al2[i], b[j],   acc[i][j], 0, 0, 0); \
      }                                                                        \
    }

#define BMM_WAIT(SEL)                                                          \
  if ((SEL) == 0) {                                                            \
    if constexpr (PROD3) asm volatile("s_waitcnt vmcnt(12)" ::: "memory");     \
    else                 asm volatile("s_waitcnt vmcnt(6)" ::: "memory");      \
  } else if ((SEL) == 1) {                                                     \
    if constexpr (PROD3) asm volatile("s_waitcnt vmcnt(8)" ::: "memory");      \
    else                 asm volatile("s_waitcnt vmcnt(4)" ::: "memory");      \
  } else if ((SEL) == 2) {                                                     \
    if constexpr (PROD3) asm volatile("s_waitcnt vmcnt(4)" ::: "memory");      \
    else                 asm volatile("s_waitcnt vmcnt(2)" ::: "memory");      \
  } else {                                                                     \
    asm volatile("s_waitcnt vmcnt(0)" ::: "memory");                           \
  }

template <int PROD3, int DMODE, int OMODE, int DUAL, int FROB, int VOUT = 0>
__global__ __launch_bounds__(256)
void k_bmm(const u16* __restrict__ Ah, const u16* __restrict__ Al,
           const u16* __restrict__ Bh, const u16* __restrict__ Bl,
           const u16* __restrict__ Dh, const u16* __restrict__ Dl,
           u16* __restrict__ Cnh, u16* __restrict__ Cnl,
           u16* __restrict__ Cth, u16* __restrict__ Ctl,
           float cd, float cs,
           const float* __restrict__ cdp, const float* __restrict__ csp,
           const float* __restrict__ cvsrc, u16* __restrict__ cvdst, int zmm,
           const u16* __restrict__ A2, const u16* __restrict__ B2,
           const u16* __restrict__ D2, u16* __restrict__ C2,
           float* __restrict__ part) {
  __shared__ __align__(16) u16 sA[5 * 2048], sB[5 * 2048];
  __shared__ __align__(16) u16 sAl[PROD3 ? 5 * 2048 : 8];
  __shared__ __align__(16) u16 sBl[PROD3 ? 5 * 2048 : 8];
  __shared__ float fred[FROB ? 4 : 1];

  if ((int)blockIdx.z >= zmm) {   // conversion side-channel
    const int zi = ((int)blockIdx.z - zmm) * 64 + blockIdx.y * 8 + blockIdx.x;
    const int chunk = zi >> 7;                     // 128 blocks per 4M chunk
    const int base = (zi & 127) * 256 + (int)threadIdx.x;
    const float* src = cvsrc + (size_t)chunk * 4194304;
    u16* dst = cvdst + (size_t)chunk * 4194304;
#pragma unroll
    for (int e = 0; e < 16; ++e) {
      const size_t g = (size_t)(base + e * 32768) * 8;
      float4 f0 = *reinterpret_cast<const float4*>(src + g);
      float4 f1 = *reinterpret_cast<const float4*>(src + g + 4);
      u16x8 w;
      w[0] = f2bf(f0.x); w[1] = f2bf(f0.y); w[2] = f2bf(f0.z); w[3] = f2bf(f0.w);
      w[4] = f2bf(f1.x); w[5] = f2bf(f1.y); w[6] = f2bf(f1.z); w[7] = f2bf(f1.w);
      *reinterpret_cast<u16x8*>(dst + g) = w;
    }
    return;
  }

  const int zq = DUAL ? ((blockIdx.z >> 3) & 1) : 0;   // 0: job A, 1: job B
  const u16* Ah_ = (DUAL && zq) ? A2 : Ah;
  const u16* Bh_ = (DUAL && zq) ? B2 : Bh;
  const u16* Dh_ = (DUAL && zq) ? D2 : Dh;
  u16* Cnh_ = (DUAL && zq) ? C2 : Cnh;
  const size_t zb = (size_t)(blockIdx.z & 7) * 262144;
  const int tid = threadIdx.x, lane = tid & 63, wave = tid >> 6;
  const int m0 = blockIdx.y * 64, n0 = blockIdx.x * 64;
  const int wr = wave >> 1, wc = wave & 1;
  const int c15 = lane & 15, lk = lane >> 4;
  const int srow = tid >> 2;
  const int sg = (tid & 3) ^ (srow & 3);            // granule-XOR (involution)
  f32x4 acc[2][2] = {};
  const u16* pa = Ah_ + zb + (size_t)(m0 + srow) * 512 + sg * 8;
  const u16* pb = Bh_ + zb + (size_t)(n0 + srow) * 512 + sg * 8;
  const u16* pal = PROD3 ? Al + zb + (size_t)(m0 + srow) * 512 + sg * 8 : pa;
  const u16* pbl = PROD3 ? Bl + zb + (size_t)(n0 + srow) * 512 + sg * 8 : pb;

  int jn = 0, js = 0;
  auto STG = [&]() {
    if (jn < 16) {
      const int off = jn << 5;
      __builtin_amdgcn_global_load_lds((const AS1 void*)(pa + off),
                                       (AS3 void*)(sA + js * 2048 + tid * 8), 16, 0, 0);
      __builtin_amdgcn_global_load_lds((const AS1 void*)(pb + off),
                                       (AS3 void*)(sB + js * 2048 + tid * 8), 16, 0, 0);
      if constexpr (PROD3) {
        __builtin_amdgcn_global_load_lds((const AS1 void*)(pal + off),
                                         (AS3 void*)(sAl + js * 2048 + tid * 8), 16, 0, 0);
        __builtin_amdgcn_global_load_lds((const AS1 void*)(pbl + off),
                                         (AS3 void*)(sBl + js * 2048 + tid * 8), 16, 0, 0);
      }
    }
    ++jn; js = (js == 4) ? 0 : js + 1;
  };

  STG(); STG(); STG();          // prefetch steps 0,1,2 (lead 3)
  int rs = 0;
  for (int t = 0; t < 13; ++t) {
    STG();                      // stage step t+3
    BMM_WAIT(0)                 // step t landed (3 steps in flight)
    __builtin_amdgcn_s_barrier();
    BMM_FRAGS(rs)
    rs = (rs == 4) ? 0 : rs + 1;
  }
  STG();                        // t=13: no-op, 2 steps out
  BMM_WAIT(1)
  __builtin_amdgcn_s_barrier();
  { BMM_FRAGS(rs) }
  rs = (rs == 4) ? 0 : rs + 1;
  STG();                        // t=14: no-op, 1 step out
  BMM_WAIT(2)
  __builtin_amdgcn_s_barrier();
  { BMM_FRAGS(rs) }
  rs = (rs == 4) ? 0 : rs + 1;
  STG();                        // t=15: no-op, full drain
  BMM_WAIT(3)
  __builtin_amdgcn_s_barrier();
  { BMM_FRAGS(rs) }

  const float cdL = cdp ? cdp[blockIdx.z & 7] : cd;
  const float csL = csp ? csp[blockIdx.z & 7] : cs;
  float fs = 0.f;
  // epilogue (C/D map: col=lane&15, row=(lane>>4)*4+r)
#pragma unroll
  for (int i = 0; i < 2; ++i)
#pragma unroll
    for (int j = 0; j < 2; ++j) {
      const int rowb = m0 + wr * 32 + i * 16 + lk * 4;
      const int col  = n0 + wc * 32 + j * 16 + c15;
      u16 hv[4], lv[4];
#pragma unroll
      for (int r = 0; r < 4; ++r) {
        float val = csL * acc[i][j][r];
        float dv = 0.f;
        if constexpr (DMODE >= 1) {
          dv = bf2f(Dh_[zb + (size_t)(rowb + r) * 512 + col]);
          if constexpr (DMODE == 2) dv += bf2f(Dl[zb + (size_t)(rowb + r) * 512 + col]);
        }
        float nval, tval;
        if constexpr (VOUT) { tval = val; nval = cdL * dv - val; }
        else { nval = tval = val + cdL * dv; }
        u16 nh = f2bf(nval);
        if constexpr (OMODE & 1) Cnh_[zb + (size_t)(rowb + r) * 512 + col] = nh;
        if constexpr (FROB) { float v = bf2f(nh); fs += v * v; }
        if constexpr (OMODE & 2)
          Cnl[zb + (size_t)(rowb + r) * 512 + col] = f2bf(nval - bf2f(nh));
        if constexpr (OMODE & 12) {
          u16 th = f2bf(tval);
          hv[r] = th;
          if constexpr (OMODE & 8) lv[r] = f2bf(tval - bf2f(th));
        }
      }
      if constexpr (OMODE & 4) {
        u16x4 v; v[0] = hv[0]; v[1] = hv[1]; v[2] = hv[2]; v[3] = hv[3];
        *reinterpret_cast<u16x4*>(&Cth[zb + (size_t)col * 512 + rowb]) = v;
      }
      if constexpr (OMODE & 8) {
        u16x4 v; v[0] = lv[0]; v[1] = lv[1]; v[2] = lv[2]; v[3] = lv[3];
        *reinterpret_cast<u16x4*>(&Ctl[zb + (size_t)col * 512 + rowb]) = v;
      }
    }
  if constexpr (FROB) {
    for (int off = 32; off; off >>= 1) fs += __shfl_down(fs, off, 64);
    if ((tid & 63) == 0) fred[tid >> 6] = fs;
    __syncthreads();
    if (tid == 0 && (int)blockIdx.z < 8)   // job A only
      part[(blockIdx.z & 7) * 64 + blockIdx.y * 8 + blockIdx.x] =
          fred[0] + fred[1] + fred[2] + fred[3];
  }
}

// ---------------- tw = W_bf @ blockdiag(Q)  (B = Qt, 5-slot ring) -----------
__global__ __launch_bounds__(256)
void k_twmm(const u16* __restrict__ W, const u16* __restrict__ Qt,
            u16* __restrict__ tw) {
  __shared__ __align__(16) u16 sA[5 * 2048], sB[5 * 2048];
  const int z = blockIdx.z;
  const size_t zb = (size_t)z * 262144;
  const int tid = threadIdx.x, lane = tid & 63, wave = tid >> 6;
  const int m0 = blockIdx.y * 64, n0 = blockIdx.x * 64;
  const int wr = wave >> 1, wc = wave & 1;
  const int c15 = lane & 15, lk = lane >> 4;
  const int srow = tid >> 2;
  const int sg = (tid & 3) ^ (srow & 3);
  f32x4 acc[2][2] = {};
  const u16* pa = W + (size_t)(m0 + srow) * 4096 + z * 512 + sg * 8;
  const u16* pb = Qt + zb + (size_t)(n0 + srow) * 512 + sg * 8;

  int jn = 0, js = 0;
  auto STG = [&]() {
    if (jn < 16) {
      const int off = jn << 5;
      __builtin_amdgcn_global_load_lds((const AS1 void*)(pa + off),
                                       (AS3 void*)(sA + js * 2048 + tid * 8), 16, 0, 0);
      __builtin_amdgcn_global_load_lds((const AS1 void*)(pb + off),
                                       (AS3 void*)(sB + js * 2048 + tid * 8), 16, 0, 0);
    }
    ++jn; js = (js == 4) ? 0 : js + 1;
  };

#define TW_FRAGS(rs)                                                           \
  {                                                                            \
    bf16x8 a[2], b[2];                                                         \
    _Pragma("unroll")                                                          \
    for (int i = 0; i < 2; ++i) {                                              \
      const int fr = wr * 32 + i * 16 + c15;                                   \
      a[i] = *reinterpret_cast<const bf16x8*>(                                 \
          &sA[(rs) * 2048 + fr * 32 + ((lk ^ (fr & 3)) * 8)]);                 \
    }                                                                          \
    _Pragma("unroll")                                                          \
    for (int j = 0; j < 2; ++j) {                                              \
      const int fc = wc * 32 + j * 16 + c15;                                   \
      b[j] = *reinterpret_cast<const bf16x8*>(                                 \
          &sB[(rs) * 2048 + fc * 32 + ((lk ^ (fc & 3)) * 8)]);                 \
    }                                                                          \
    _Pragma("unroll")                                                          \
    for (int i = 0; i < 2; ++i)                                                \
      _Pragma("unroll")                                                        \
      for (int j = 0; j < 2; ++j)                                              \
        acc[i][j] = __builtin_amdgcn_mfma_f32_16x16x32_bf16(a[i], b[j], acc[i][j], 0, 0, 0); \
  }

  STG(); STG(); STG();
  int rs = 0;
  for (int t = 0; t < 13; ++t) {
    STG();
    asm volatile("s_waitcnt vmcnt(6)" ::: "memory");
    __builtin_amdgcn_s_barrier();
    TW_FRAGS(rs)
    rs = (rs == 4) ? 0 : rs + 1;
  }
  STG();
  asm volatile("s_waitcnt vmcnt(4)" ::: "memory");
  __builtin_amdgcn_s_barrier();
  TW_FRAGS(rs)
  rs = (rs == 4) ? 0 : rs + 1;
  STG();
  asm volatile("s_waitcnt vmcnt(2)" ::: "memory");
  __builtin_amdgcn_s_barrier();
  TW_FRAGS(rs)
  rs = (rs == 4) ? 0 : rs + 1;
  STG();
  asm volatile("s_waitcnt vmcnt(0)" ::: "memory");
  __builtin_amdgcn_s_barrier();
  TW_FRAGS(rs)

#pragma unroll
  for (int i = 0; i < 2; ++i)
#pragma unroll
    for (int j = 0; j < 2; ++j) {
      const int rowb = m0 + wr * 32 + i * 16 + lk * 4;
      const int col  = z * 512 + n0 + wc * 32 + j * 16 + c15;
#pragma unroll
      for (int r = 0; r < 4; ++r)
        tw[(size_t)(rowb + r) * 4096 + col] = f2bf(acc[i][j][r]);
    }
}

// ---------------- out = x_bf @ tw^T + bias (round-6, verbatim) --------------
#define NSL 18

#define RD_A3(dst, MH)                                                         \
  _Pragma("unroll")                                                            \
  for (int m = 0; m < 4; ++m)                                                  \
    dst[m] = *reinterpret_cast<const bf16x8*>(                                 \
        &lds[aslot * 4096 + ((MH) * 64 + m * 16 + c15) * 32 + gsw * 8]);

#define RD_B3(dst)                                                             \
  _Pragma("unroll")                                                            \
  for (int n = 0; n < 4; ++n)                                                  \
    dst[n] = *reinterpret_cast<const bf16x8*>(                                 \
        &lds[bslot * 4096 + (bq64 + n * 16 + c15) * 32 + gsw * 8]);

#define MFMA16(afX, bfX, MH)                                                   \
  __builtin_amdgcn_s_setprio(1);                                               \
  _Pragma("unroll")                                                            \
  for (int m = 0; m < 4; ++m)                                                  \
    _Pragma("unroll")                                                          \
    for (int n = 0; n < 4; ++n)                                                \
      acc[(MH) * 4 + m][n] = __builtin_amdgcn_mfma_f32_16x16x32_bf16(          \
          afX[m], bfX[n], acc[(MH) * 4 + m][n], 0, 0, 0);                      \
  __builtin_amdgcn_s_setprio(0);

// WM: 1 steady vmcnt(8) | 2 vmcnt(4) | 3 vmcnt(0) | 0 none (last tile)
#define TILE32(WM)                                                             \
  {                                                                            \
    int aslot = s0 + wr;            if (aslot >= NSL) aslot -= NSL;            \
    int bslot = s0 + 2 + (wc >> 1); if (bslot >= NSL) bslot -= NSL;            \
    STAGE(); STAGE();                                                          \
    RD_B3(bfr)                                                                 \
    RD_A3(afA, 0)                                                              \
    MFMA16(afA, bfr, 0)                                                        \
    STAGE(); STAGE();                                                          \
    RD_A3(afB, 1)                                                              \
    MFMA16(afB, bfr, 1)                                                        \
    if ((WM) == 1) asm volatile("s_waitcnt vmcnt(8)" ::: "memory");            \
    if ((WM) == 2) asm volatile("s_waitcnt vmcnt(4)" ::: "memory");            \
    if ((WM) == 3) asm volatile("s_waitcnt vmcnt(0)" ::: "memory");            \
    if ((WM) != 0) {                                                           \
      __builtin_amdgcn_s_barrier();                                            \
      __builtin_amdgcn_sched_barrier(0);                                       \
    }                                                                          \
    s0 += 4; if (s0 >= NSL) s0 -= NSL;                                         \
  }

__global__ __launch_bounds__(512, 2)
void k_gemm256(const u16* __restrict__ A, const u16* __restrict__ B,
               const float* __restrict__ bias,
               float* __restrict__ C, int N, int K) {
  __shared__ __align__(16) u16 lds[NSL * 4096];   // 144 KiB
  const int tid = threadIdx.x, lane = tid & 63, wave = tid >> 6;
  int bid = blockIdx.y * gridDim.x + blockIdx.x;
  const int cpx = (gridDim.x * gridDim.y) >> 3;
  bid = (bid & 7) * cpx + (bid >> 3);
  const int nbx = N >> 8;
  const int bx = bid % nbx, by = bid / nbx;
  const int m0 = by << 8, n0 = bx << 8;
  const int wr = wave >> 2, wc = wave & 3;          // 2 x 4 wave grid
  const int srow = tid >> 2;
  const int sgc  = (tid & 3) ^ ((srow >> 1) & 3);
  const int c15 = lane & 15, lq = lane >> 4;
  const int gsw = lq ^ ((c15 >> 1) & 3);
  const int bq64 = (wc & 1) * 64;
  const int NT = K >> 5;                            // 128

  f32x4 acc[8][4] = {};
  bf16x8 afA[4], afB[4], bfr[4];

  int jn = 0, js = 0;
  auto STAGE = [&]() {
    if (jn < 4 * NT) {
      const int t = jn >> 2, q = jn & 3;
      const u16* srcb = (q < 2)
          ? A + (size_t)(m0 + q * 128 + srow) * (size_t)K
          : B + (size_t)(n0 + (q - 2) * 128 + srow) * (size_t)K;
      const u16* src = srcb + (t << 5) + sgc * 8;
      u16* dst = (u16*)lds + js * 4096 + tid * 8;
      __builtin_amdgcn_global_load_lds(
          (const AS1 void*)src, (AS3 void*)dst, 16, 0, 0);
    }
    ++jn; js = (js == NSL - 1) ? 0 : js + 1;
  };

#pragma unroll
  for (int i = 0; i < 12; ++i) STAGE();
  asm volatile("s_waitcnt vmcnt(8)" ::: "memory");
  __builtin_amdgcn_s_barrier();
  __builtin_amdgcn_sched_barrier(0);

  int s0 = 0;
  for (int tau = 0; tau < NT - 3; ++tau) {
    TILE32(1)
  }
  TILE32(2)
  TILE32(3)
  TILE32(0)

#pragma unroll
  for (int n = 0; n < 4; ++n) {
    const int col = n0 + wc * 64 + n * 16 + c15;
    const float bv = bias[col];
#pragma unroll
    for (int mi = 0; mi < 8; ++mi) {
      const int rowb = m0 + wr * 128 + mi * 16 + (lq << 2);
#pragma unroll
      for (int r = 0; r < 4; ++r)
        C[(size_t)(rowb + r) * N + col] = acc[mi][n][r] + bv;
    }
  }
}

extern "C" void kernel_launch(void* const* d_in, const int* in_sizes, int n_in,
                              void* d_out, int out_size, void* d_ws, size_t ws_size,
                              hipStream_t stream) {
  const float* W    = (const float*)d_in[0];   // [4096,4096]
  const float* bias = (const float*)d_in[1];   // [4096]
  const float* x    = (const float*)d_in[2];   // [4,2048,4096]
  const float* R    = (const float*)d_in[3];   // [8,512,512]
  float* out = (float*)d_out;

  char* ws = (char*)d_ws;
  u16* x_bf = (u16*)(ws);                      //  64 MiB
  u16* tw   = (u16*)(ws + 67108864);           //  32 MiB
  u16* W_bf = (u16*)(ws + 100663296);          //  32 MiB

  // scratch arena = d_out (128 MiB; fully overwritten by k_gemm256)
  char* arena = (char*)d_out;
  auto slot = [&](int i) -> u16* { return (u16*)(arena + (size_t)i * 4194304); };
  u16 *Mh = slot(0), *Ml = slot(1);
  u16 *G = slot(2), *G2 = slot(3), *H = slot(4);
  u16 *T2 = slot(6), *X1 = slot(7), *X2 = slot(8), *T3 = slot(9);
  u16 *X3h = slot(10), *X3l = slot(11), *X3th = slot(12), *X3tl = slot(13);
  u16 *Tpth = slot(14), *Tptl = slot(15);
  u16 *Vh = slot(16), *Vl = slot(17);
  u16 *Qt = slot(20);
  float* coef = (float*)(arena + (size_t)21 * 4194304);   // 72 floats
  float* part = coef + 1024;                              // 512 floats

  const u16* NUL = nullptr;
  const float* NULF = nullptr;
  u16* NULW = nullptr;
  float* NULP = nullptr;
  const dim3 gC2(8, 8, 12);     // 8 mm + 4 conv planes (2 chunks)
  const dim3 gD2(8, 8, 20);     // 16 mm (DUAL) + 4 conv planes (2 chunks)

  // 1) M pair
  k_build_M<<<dim3(16, 16, 8), 256, 0, stream>>>(R, Mh, Ml);
  // 2) G = M@M^T (+ W chunks 0,1)
  k_bmm<0, 0, 1, 0, 0><<<gC2, 256, 0, stream>>>(Mh, NUL, Mh, NUL, NUL, NUL,
      G, NULW, NULW, NULW, 0.f, 1.f, NULF, NULF, W, W_bf, 8,
      NUL, NUL, NUL, NULW, NULP);
  // 3) DUAL: G2 = G@G (+frob partials)  ||  H = M@G   (+ W chunks 2,3)
  k_bmm<0, 0, 1, 1, 1><<<gD2, 256, 0, stream>>>(G, NUL, G, NUL, NUL, NUL,
      G2, NULW, NULW, NULW, 0.f, 1.f, NULF, NULF,
      W + (size_t)2 * 4194304, W_bf + (size_t)2 * 4194304, 16,
      Mh, G, NUL, H, part);
  // 4) coefficients ; X1 (elementwise: g0 I + g1 M + g2 G + g3 H) + T2
  k_init<<<1024, 256, 0, stream>>>(Mh, Ml, G, G2, H, part, coef, X1, T2);
  // 5) DUAL: X2 = 2c2*X1 - c2*(X1@T2)  ||  T3 = 2c2*T2 - c2*(T2@T2)
  //    (+ x chunks 0,1)
  k_bmm<0, 1, 1, 1, 0><<<gD2, 256, 0, stream>>>(X1, NUL, T2, NUL, X1, NUL,
      X2, NULW, NULW, NULW, 0.f, 0.f, coef + 40, coef + 48,
      x, x_bf, 16, T2, T2, T2, T3, NULP);
  // 6) X3 = 2c3*X2 - c3*(X2@T3), pairs + transposed pairs  (+ x chunks 2,3)
  k_bmm<0, 1, 15, 0, 0><<<gC2, 256, 0, stream>>>(X2, NUL, T3, NUL, X2, NUL,
      X3h, X3l, X3th, X3tl, 0.f, 0.f, coef + 56, coef + 64,
      x + (size_t)2 * 4194304, x_bf + (size_t)2 * 4194304, 8,
      NUL, NUL, NUL, NULW, NULP);
  // 7) VOUT: Tp^T = (M@X3)^T pairs  AND  V = C1Q*X3 - Tp pairs
  //    (+ x chunks 4,5)
  k_bmm<1, 2, 15, 0, 0, 1><<<gC2, 256, 0, stream>>>(Mh, Ml, X3th, X3tl,
      X3h, X3l, Vh, Vl, Tpth, Tptl, C1Q, 1.f, NULF, NULF,
      x + (size_t)4 * 4194304, x_bf + (size_t)4 * 4194304, 8,
      NUL, NUL, NUL, NULW, NULP);
  // 8) Q^T = transpose of (2V - V@Tp)  (+ x chunks 6,7)
  k_bmm<1, 2, 4, 0, 0><<<gC2, 256, 0, stream>>>(Vh, Vl, Tpth, Tptl, Vh, Vl,
      NULW, NULW, Qt, NULW, 2.f, -1.f, NULF, NULF,
      x + (size_t)6 * 4194304, x_bf + (size_t)6 * 4194304, 8,
      NUL, NUL, NUL, NULW, NULP);
  // 9) tw = W_bf @ blockdiag(Q) ; main GEMM (overwrites the arena)
  k_twmm<<<dim3(8, 64, 8), 256, 0, stream>>>(W_bf, Qt, tw);
  k_gemm256<<<dim3(16, 32), 512, 0, stream>>>(x_bf, tw, bias, out, 4096, 4096);
}